// Round 1
// 57.677 us; speedup vs baseline: 1.2011x; 1.2011x over previous
//
#include <hip/hip_runtime.h>

// Quantum classifier, 20 qubits, depth-2 hardware-efficient ansatz.
//
// ANALYTIC REDUCTION (Heisenberg picture / Pauli back-propagation):
// The measured feature for qubit q is -<Z_q> of the final state. Conjugating
// Z_q backward through U = CZ . RY(th1) . CZ . RY(th0) . RX(x):
//   <Z_q> = cos(t1q) cos(t0q) cos(x_q)
//         - sin(t1q) sin(t0q) cos(x_q) * PROD_{j in nbrs(q)} cos(t0j) cos(x_j)
//   features[b,q] = -<Z_q>,  logits = features @ W^T + b.
// Exact for all inputs; only fp32 trig rounding remains.
//
// ROUND-1 PERF ANALYSIS: single wave, VALUBusy ~0, HBM ~0 -> pure serial
// latency. ~120 libm cosf/sinf calls (inlined __ocml, ~40 instrs each,
// fully unrolled => ~20 KB code) dominate via dependent-chain latency and
// serial I$ misses (FETCH_SIZE 19 KB vs ~3 KB of data = code fetch).
// FIX: HIP native __cosf/__sinf -> v_cos_f32/v_sin_f32 (1 instr + mul by
// 1/2pi, inputs < 1 revolution, well inside HW-accurate domain), and
// float4-vectorized loads (rows are 80 B = 16 B aligned).

#define N_QUBITS 20

__global__ __launch_bounds__(64) void qc_analytic_kernel(
    const float* __restrict__ x,      // (32, 20)
    const float* __restrict__ theta,  // (2, 20)  theta0=theta[q], theta1=theta[20+q]
    const float* __restrict__ W,      // (2, 20)
    const float* __restrict__ bias,   // (2,)
    float* __restrict__ out)          // (32, 2)
{
    const int t = threadIdx.x;   // 0..63
    const int bidx = t >> 1;     // batch element 0..31
    const int k = t & 1;         // output class 0..1

    // ---- vectorized loads: x row (80 B), theta (160 B), W row (80 B) ----
    float xv[N_QUBITS];
    {
        const float4* p = reinterpret_cast<const float4*>(x + bidx * N_QUBITS);
#pragma unroll
        for (int i = 0; i < N_QUBITS / 4; ++i) {
            float4 v = p[i];
            xv[4 * i + 0] = v.x; xv[4 * i + 1] = v.y;
            xv[4 * i + 2] = v.z; xv[4 * i + 3] = v.w;
        }
    }
    float th0[N_QUBITS], th1[N_QUBITS];
    {
        const float4* p = reinterpret_cast<const float4*>(theta);
#pragma unroll
        for (int i = 0; i < N_QUBITS / 4; ++i) {
            float4 v = p[i];
            th0[4 * i + 0] = v.x; th0[4 * i + 1] = v.y;
            th0[4 * i + 2] = v.z; th0[4 * i + 3] = v.w;
        }
#pragma unroll
        for (int i = 0; i < N_QUBITS / 4; ++i) {
            float4 v = p[N_QUBITS / 4 + i];
            th1[4 * i + 0] = v.x; th1[4 * i + 1] = v.y;
            th1[4 * i + 2] = v.z; th1[4 * i + 3] = v.w;
        }
    }
    float wv[N_QUBITS];
    {
        const float4* p = reinterpret_cast<const float4*>(W + k * N_QUBITS);
#pragma unroll
        for (int i = 0; i < N_QUBITS / 4; ++i) {
            float4 v = p[i];
            wv[4 * i + 0] = v.x; wv[4 * i + 1] = v.y;
            wv[4 * i + 2] = v.z; wv[4 * i + 3] = v.w;
        }
    }

    // ---- hardware trig (v_cos_f32 / v_sin_f32), all independent => pipelined
    float c[N_QUBITS];    // cos(x_bq)
    float ct0[N_QUBITS], st0[N_QUBITS], ct1[N_QUBITS], st1[N_QUBITS];
    float cc[N_QUBITS];   // cos(theta0_q) * cos(x_bq)  (neighbor factor)
#pragma unroll
    for (int q = 0; q < N_QUBITS; ++q) {
        c[q]   = __cosf(xv[q]);
        ct0[q] = __cosf(th0[q]);
        st0[q] = __sinf(th0[q]);
        ct1[q] = __cosf(th1[q]);
        st1[q] = __sinf(th1[q]);
        cc[q]  = ct0[q] * c[q];
    }

    float acc = bias[k];
#pragma unroll
    for (int q = 0; q < N_QUBITS; ++q) {
        float prod = 1.0f;
        if (q > 0)            prod *= cc[q - 1];
        if (q < N_QUBITS - 1) prod *= cc[q + 1];
        const float z = ct1[q] * ct0[q] * c[q]
                      - st1[q] * st0[q] * c[q] * prod;
        acc += (-z) * wv[q];
    }

    out[bidx * 2 + k] = acc;
}

extern "C" void kernel_launch(void* const* d_in, const int* in_sizes, int n_in,
                              void* d_out, int out_size, void* d_ws, size_t ws_size,
                              hipStream_t stream) {
    const float* x     = (const float*)d_in[0];  // 32*20
    const float* theta = (const float*)d_in[1];  // 2*20
    const float* W     = (const float*)d_in[2];  // 2*20
    const float* bias  = (const float*)d_in[3];  // 2
    float* out = (float*)d_out;                  // 64

    qc_analytic_kernel<<<1, 64, 0, stream>>>(x, theta, W, bias, out);
}